// Round 1
// baseline (58.965 us; speedup 1.0000x reference)
//
#include <hip/hip_runtime.h>

// QuantizedLinear: out[8,8192] = x[8,8192] @ W^T, W = dequant4(qweight, scale, zero)
// qweight packed 2 nibbles/byte (low nibble first), delivered as int32 (0..255).
// GROUP=128 -> 64 packed ints per group -> one group per wave-iteration.

constexpr int M      = 8;
constexpr int OUTF   = 8192;
constexpr int INF    = 8192;
constexpr int NGROUP = 64;          // IN / GROUP
constexpr int PKROW  = INF / 2;     // 4096 packed elements per output row
constexpr int RPW    = 4;           // rows per wave
constexpr int WPB    = 4;           // waves per block (256 threads)

__global__ __launch_bounds__(256, 2) void qlin4_kernel(
    const float* __restrict__ x,      // [8, 8192]
    const int*   __restrict__ qw,     // [8192, 4096] values 0..255
    const float* __restrict__ scale,  // [8192, 64]
    const float* __restrict__ zero,   // [8192, 64]
    float*       __restrict__ out)    // [8, 8192]
{
    const int lane = threadIdx.x & 63;
    const int wave = threadIdx.x >> 6;
    const int n0   = (blockIdx.x * WPB + wave) * RPW;   // first output row of this wave

    float acc[M][RPW];
    #pragma unroll
    for (int m = 0; m < M; ++m)
        #pragma unroll
        for (int r = 0; r < RPW; ++r) acc[m][r] = 0.0f;

    const float2* __restrict__ x2 = reinterpret_cast<const float2*>(x);  // [8][4096]

    for (int g = 0; g < NGROUP; ++g) {
        // Packed weights: lane l covers k = g*128 + 2l, 2l+1 for each of RPW rows.
        int q[RPW];
        #pragma unroll
        for (int r = 0; r < RPW; ++r)
            q[r] = qw[(size_t)(n0 + r) * PKROW + (g * 64 + lane)];

        // Wave-uniform scale/zero for this group (scalar loads).
        float s[RPW], zs[RPW];
        #pragma unroll
        for (int r = 0; r < RPW; ++r) {
            const float sc = scale[(n0 + r) * NGROUP + g];
            s[r]  = sc;
            zs[r] = zero[(n0 + r) * NGROUP + g] * sc;
        }

        // Dequant once per row (hoisted out of the m loop): w = q*s - z*s
        float wl[RPW], wh[RPW];
        #pragma unroll
        for (int r = 0; r < RPW; ++r) {
            wl[r] = fmaf((float)(q[r] & 15),        s[r], -zs[r]);
            wh[r] = fmaf((float)((q[r] >> 4) & 15), s[r], -zs[r]);
        }

        // Accumulate against all 8 activation rows; float2 = the two k positions.
        #pragma unroll
        for (int m = 0; m < M; ++m) {
            const float2 xv = x2[m * (INF / 2) + g * 64 + lane];
            #pragma unroll
            for (int r = 0; r < RPW; ++r) {
                acc[m][r] = fmaf(wl[r], xv.x, acc[m][r]);
                acc[m][r] = fmaf(wh[r], xv.y, acc[m][r]);
            }
        }
    }

    // Wave-wide butterfly reduction (each lane held a partial over its k slice).
    #pragma unroll
    for (int m = 0; m < M; ++m) {
        #pragma unroll
        for (int r = 0; r < RPW; ++r) {
            float v = acc[m][r];
            #pragma unroll
            for (int off = 32; off > 0; off >>= 1)
                v += __shfl_xor(v, off, 64);
            acc[m][r] = v;
        }
    }

    if (lane == 0) {
        #pragma unroll
        for (int m = 0; m < M; ++m)
            #pragma unroll
            for (int r = 0; r < RPW; ++r)
                out[m * OUTF + (n0 + r)] = acc[m][r];
    }
}

extern "C" void kernel_launch(void* const* d_in, const int* in_sizes, int n_in,
                              void* d_out, int out_size, void* d_ws, size_t ws_size,
                              hipStream_t stream) {
    const float* x     = (const float*)d_in[0];
    const int*   qw    = (const int*)d_in[1];
    const float* scale = (const float*)d_in[2];
    const float* zero  = (const float*)d_in[3];
    float*       out   = (float*)d_out;

    const int blocks = OUTF / (WPB * RPW);  // 8192 / 16 = 512
    qlin4_kernel<<<blocks, 256, 0, stream>>>(x, qw, scale, zero, out);
}